// Round 2
// baseline (9275.960 us; speedup 1.0000x reference)
//
#include <hip/hip_runtime.h>
#include <hip/hip_bf16.h>

typedef __attribute__((ext_vector_type(8))) short  bf16x8;
typedef __attribute__((ext_vector_type(4))) float  f32x4;

#define EOS 2
#define S 1024
#define B 64
#define E 256
#define H 512
#define NW 128   // persistent waves: 32 unit-groups x 4 batch-slices

// f32 -> bf16, round-to-nearest-even (used for weights / h planes)
__device__ __forceinline__ unsigned short f2bf(float f) {
    unsigned int u = __builtin_bit_cast(unsigned int, f);
    unsigned int r = (u + 0x7FFFu + ((u >> 16) & 1u)) >> 16;
    return (unsigned short)r;
}
__device__ __forceinline__ float bf2f(unsigned short s) {
    unsigned int u = ((unsigned int)s) << 16;
    return __builtin_bit_cast(float, u);
}
// pack pair with round-half-up (cheap, for per-step emb conversion)
__device__ __forceinline__ unsigned int pk2(float x, float y) {
    unsigned int ux = __builtin_bit_cast(unsigned int, x) + 0x8000u;
    unsigned int uy = __builtin_bit_cast(unsigned int, y) + 0x8000u;
    return (ux >> 16) | (uy & 0xFFFF0000u);
}
__device__ __forceinline__ bf16x8 pack8hu(float4 a, float4 b) {
    union { unsigned int d[4]; bf16x8 v; } u;
    u.d[0] = pk2(a.x, a.y); u.d[1] = pk2(a.z, a.w);
    u.d[2] = pk2(b.x, b.y); u.d[3] = pk2(b.z, b.w);
    return u.v;
}
__device__ __forceinline__ bf16x8 pack8rne(float4 a, float4 b) {
    union { unsigned short s[8]; bf16x8 v; } u;
    u.s[0] = f2bf(a.x); u.s[1] = f2bf(a.y); u.s[2] = f2bf(a.z); u.s[3] = f2bf(a.w);
    u.s[4] = f2bf(b.x); u.s[5] = f2bf(b.y); u.s[6] = f2bf(b.z); u.s[7] = f2bf(b.w);
    return u.v;
}

// ---------------------------------------------------------------------------
// dest[t][b] = k-th EOS index (0..31) or -1
// ---------------------------------------------------------------------------
__global__ __launch_bounds__(256) void dest_kernel(const int* __restrict__ tokens,
                                                   int* __restrict__ dest) {
    const int b = blockIdx.x, tid = threadIdx.x;
    const int l = tid & 63, w = tid >> 6;
    const int base = tid * 4;
    int m[4], cnt = 0;
#pragma unroll
    for (int i = 0; i < 4; ++i) {
        int tok = tokens[b * S + base + i];
        m[i] = (tok == EOS) ? 1 : 0;
        cnt += m[i];
    }
    int inc = cnt;
#pragma unroll
    for (int d = 1; d < 64; d <<= 1) {
        int v = __shfl_up(inc, d, 64);
        if (l >= d) inc += v;
    }
    __shared__ int wt[4];
    if (l == 63) wt[w] = inc;
    __syncthreads();
    int off = 0;
    for (int k = 0; k < 4; ++k)
        if (k < w) off += wt[k];
    int run = off + inc - cnt;  // exclusive prefix
#pragma unroll
    for (int i = 0; i < 4; ++i) {
        dest[(base + i) * B + b] = m[i] ? run : -1;
        run += m[i];
    }
}

// ---------------------------------------------------------------------------
// Persistent fused GRU. 128 blocks x 64 threads (one wave each, no LDS).
// Wave wid: unit group j=wid>>2 (units [16j,16j+16)), batch slice w=wid&3
// (batches [16w,16w+16)). W_hh/W_ih fragments register-resident (288 VGPRs,
// 1 wave/SIMD -> 512 budget). h exchanged via global bf16 hi+lo planes,
// double-buffered; per-wave flags with agent-scope fence protocol.
// ---------------------------------------------------------------------------
__global__ __launch_bounds__(64, 1) void gru_kernel(
    const int* __restrict__ tokens, const float* __restrict__ emb,
    const float* __restrict__ w_ih, const float* __restrict__ w_hh,
    const float* __restrict__ b_ih, const float* __restrict__ b_hh,
    const int* __restrict__ dest,
    unsigned short* hbuf, unsigned int* flags, float* __restrict__ out) {

    const int wid = blockIdx.x;          // 0..127
    const int j = wid >> 2;              // unit group
    const int w = wid & 3;               // batch slice
    const int l = threadIdx.x;           // 0..63
    const int l15 = l & 15, quad = l >> 4;
    const int unit = j * 16 + l15;       // B-frag n-row (this lane's unit)
    const int koff = quad * 8;           // k offset within 32-chunk
    const int brow = w * 16 + l15;       // A-frag m-row (this lane's batch)

    // ---- one-time: weight B-fragments into registers (RNE bf16) ----
    bf16x8 Wh[3][16];
#pragma unroll
    for (int g = 0; g < 3; ++g)
#pragma unroll
        for (int kt = 0; kt < 16; ++kt) {
            const float* p = &w_hh[(size_t)(g * H + unit) * H + kt * 32 + koff];
            Wh[g][kt] = pack8rne(*(const float4*)p, *(const float4*)(p + 4));
        }
    bf16x8 Wi[3][8];
#pragma unroll
    for (int g = 0; g < 3; ++g)
#pragma unroll
        for (int kt = 0; kt < 8; ++kt) {
            const float* p = &w_ih[(size_t)(g * H + unit) * E + kt * 32 + koff];
            Wi[g][kt] = pack8rne(*(const float4*)p, *(const float4*)(p + 4));
        }
    const float bi0 = b_ih[unit], bi1 = b_ih[H + unit], bi2 = b_ih[2 * H + unit];
    const float bh0 = b_hh[unit], bh1 = b_hh[H + unit], bh2 = b_hh[2 * H + unit];

    float hown[4] = {0.f, 0.f, 0.f, 0.f};
    int tok_next = tokens[brow * S];     // token for t=0
    int budget = 1 << 22;                // anti-hang safety

    for (int t = 0; t < S; ++t) {
        // --- independent work first (hides under producer/consumer wait) ---
        const int tok = tok_next;
        const float* er = &emb[(size_t)tok * E + koff];
        float4 ef[8][2];
#pragma unroll
        for (int kt = 0; kt < 8; ++kt) {
            ef[kt][0] = *(const float4*)(er + kt * 32);
            ef[kt][1] = *(const float4*)(er + kt * 32 + 4);
        }
        if (t + 1 < S) tok_next = tokens[brow * S + t + 1];
        int4 dst4 = *(const int4*)&dest[t * B + w * 16 + quad * 4];

        f32x4 gi0 = {bi0, bi0, bi0, bi0};
        f32x4 gi1 = {bi1, bi1, bi1, bi1};
        f32x4 gi2 = {bi2, bi2, bi2, bi2};
#pragma unroll
        for (int kt = 0; kt < 8; ++kt) {
            bf16x8 af = pack8hu(ef[kt][0], ef[kt][1]);
            gi0 = __builtin_amdgcn_mfma_f32_16x16x32_bf16(af, Wi[0][kt], gi0, 0, 0, 0);
            gi1 = __builtin_amdgcn_mfma_f32_16x16x32_bf16(af, Wi[1][kt], gi1, 0, 0, 0);
            gi2 = __builtin_amdgcn_mfma_f32_16x16x32_bf16(af, Wi[2][kt], gi2, 0, 0, 0);
        }

        // --- wait for h[t] (all 128 producer waves done with step t-1) ---
        while (budget > 0) {
            unsigned int f0 = __hip_atomic_load(&flags[l], __ATOMIC_RELAXED,
                                                __HIP_MEMORY_SCOPE_AGENT);
            unsigned int f1 = __hip_atomic_load(&flags[64 + l], __ATOMIC_RELAXED,
                                                __HIP_MEMORY_SCOPE_AGENT);
            if (__all((f0 >= (unsigned)t) && (f1 >= (unsigned)t))) break;
            --budget;
        }
        __builtin_amdgcn_fence(__ATOMIC_ACQUIRE, "agent");

        // --- gh = b_hh + h . W_hh^T  (h as bf16 hi+lo split: ~fp32 exact) ---
        const unsigned short* hs_hi = hbuf + (size_t)(t & 1) * (2 * B * H);
        const unsigned short* hs_lo = hs_hi + B * H;
        f32x4 a0 = {bh0, bh0, bh0, bh0};
        f32x4 a1 = {bh1, bh1, bh1, bh1};
        f32x4 a2 = {bh2, bh2, bh2, bh2};
#pragma unroll
        for (int kt = 0; kt < 16; ++kt) {
            bf16x8 ah = *(const bf16x8*)&hs_hi[brow * H + kt * 32 + koff];
            bf16x8 al = *(const bf16x8*)&hs_lo[brow * H + kt * 32 + koff];
            a0 = __builtin_amdgcn_mfma_f32_16x16x32_bf16(ah, Wh[0][kt], a0, 0, 0, 0);
            a1 = __builtin_amdgcn_mfma_f32_16x16x32_bf16(ah, Wh[1][kt], a1, 0, 0, 0);
            a2 = __builtin_amdgcn_mfma_f32_16x16x32_bf16(ah, Wh[2][kt], a2, 0, 0, 0);
            a0 = __builtin_amdgcn_mfma_f32_16x16x32_bf16(al, Wh[0][kt], a0, 0, 0, 0);
            a1 = __builtin_amdgcn_mfma_f32_16x16x32_bf16(al, Wh[1][kt], a1, 0, 0, 0);
            a2 = __builtin_amdgcn_mfma_f32_16x16x32_bf16(al, Wh[2][kt], a2, 0, 0, 0);
        }

        // --- gates + write h[t+1] ---
        unsigned short* hd_hi = hbuf + (size_t)((t + 1) & 1) * (2 * B * H);
        unsigned short* hd_lo = hd_hi + B * H;
        int dsts[4] = {dst4.x, dst4.y, dst4.z, dst4.w};
#pragma unroll
        for (int r = 0; r < 4; ++r) {
            const int b = w * 16 + quad * 4 + r;
            float rg = 1.f / (1.f + __expf(-(gi0[r] + a0[r])));
            float zg = 1.f / (1.f + __expf(-(gi1[r] + a1[r])));
            float x = gi2[r] + rg * a2[r];
            x = fminf(15.f, fmaxf(-15.f, x));
            float e = __expf(-2.f * x);
            float ng = (1.f - e) / (1.f + e);
            float h = (1.f - zg) * ng + zg * hown[r];   // fp32 carry (exact)
            hown[r] = h;
            if (dsts[r] >= 0)
                out[((size_t)(dsts[r] * B + b)) * H + unit] = h;
            unsigned short hi = f2bf(h);
            hd_hi[b * H + unit] = hi;
            hd_lo[b * H + unit] = f2bf(h - bf2f(hi));
        }

        __builtin_amdgcn_fence(__ATOMIC_RELEASE, "agent");
        if (l == 0)
            __hip_atomic_store(&flags[wid], (unsigned)(t + 1), __ATOMIC_RELAXED,
                               __HIP_MEMORY_SCOPE_AGENT);
    }
}

// ---------------------------------------------------------------------------
// Workspace layout (total ~787 KB — small on purpose; round-1 crash was
// almost certainly a 403 MB d_ws overflow):
//   [0, 512)            flags: 128 uint (zeroed)
//   [1024, 1024+512K)   hbuf: 2 bufs x {hi,lo} x [64][512] bf16 (buf0 = h0 = 0)
//   [525312, +256K)     dest map [1024][64] int32
// ---------------------------------------------------------------------------
extern "C" void kernel_launch(void* const* d_in, const int* in_sizes, int n_in,
                              void* d_out, int out_size, void* d_ws, size_t ws_size,
                              hipStream_t stream) {
    const int*   tokens = (const int*)d_in[0];
    const float* emb    = (const float*)d_in[1];
    const float* w_ih   = (const float*)d_in[2];
    const float* w_hh   = (const float*)d_in[3];
    const float* b_ih   = (const float*)d_in[4];
    const float* b_hh   = (const float*)d_in[5];
    float* out = (float*)d_out;

    char* ws = (char*)d_ws;
    unsigned int*   flags = (unsigned int*)ws;
    unsigned short* hbuf  = (unsigned short*)(ws + 1024);
    int*            dest  = (int*)(ws + 1024 + 2 * 2 * B * H * sizeof(unsigned short));

    hipMemsetAsync(d_ws, 0, 1024 + 2 * 2 * B * H * sizeof(unsigned short), stream);
    dest_kernel<<<B, 256, 0, stream>>>(tokens, dest);
    gru_kernel<<<NW, 64, 0, stream>>>(tokens, emb, w_ih, w_hh, b_ih, b_hh,
                                      dest, hbuf, flags, out);
}

// Round 3
// 7047.758 us; speedup vs baseline: 1.3162x; 1.3162x over previous
//
#include <hip/hip_runtime.h>
#include <hip/hip_bf16.h>

typedef __attribute__((ext_vector_type(8))) short  bf16x8;
typedef __attribute__((ext_vector_type(4))) float  f32x4;

#define EOS 2
#define S 1024
#define B 64
#define E 256
#define H 512
#define NW 128   // persistent waves: 32 unit-groups x 4 batch-slices

#define AT_LD(p)    __hip_atomic_load((p), __ATOMIC_RELAXED, __HIP_MEMORY_SCOPE_AGENT)
#define AT_ST(p, v) __hip_atomic_store((p), (v), __ATOMIC_RELAXED, __HIP_MEMORY_SCOPE_AGENT)

// f32 -> bf16 RNE
__device__ __forceinline__ unsigned short f2bf(float f) {
    unsigned int u = __builtin_bit_cast(unsigned int, f);
    unsigned int r = (u + 0x7FFFu + ((u >> 16) & 1u)) >> 16;
    return (unsigned short)r;
}
__device__ __forceinline__ float bf2f(unsigned short s) {
    unsigned int u = ((unsigned int)s) << 16;
    return __builtin_bit_cast(float, u);
}
__device__ __forceinline__ unsigned int pk2(float x, float y) {  // round-half-up pair
    unsigned int ux = __builtin_bit_cast(unsigned int, x) + 0x8000u;
    unsigned int uy = __builtin_bit_cast(unsigned int, y) + 0x8000u;
    return (ux >> 16) | (uy & 0xFFFF0000u);
}
__device__ __forceinline__ bf16x8 pack8hu(float4 a, float4 b) {
    union { unsigned int d[4]; bf16x8 v; } u;
    u.d[0] = pk2(a.x, a.y); u.d[1] = pk2(a.z, a.w);
    u.d[2] = pk2(b.x, b.y); u.d[3] = pk2(b.z, b.w);
    return u.v;
}
__device__ __forceinline__ bf16x8 pack8rne(float4 a, float4 b) {
    union { unsigned short s[8]; bf16x8 v; } u;
    u.s[0] = f2bf(a.x); u.s[1] = f2bf(a.y); u.s[2] = f2bf(a.z); u.s[3] = f2bf(a.w);
    u.s[4] = f2bf(b.x); u.s[5] = f2bf(b.y); u.s[6] = f2bf(b.z); u.s[7] = f2bf(b.w);
    return u.v;
}

// ---------------------------------------------------------------------------
// dest[t][b] = k-th EOS index (0..31) or -1
// ---------------------------------------------------------------------------
__global__ __launch_bounds__(256) void dest_kernel(const int* __restrict__ tokens,
                                                   int* __restrict__ dest) {
    const int b = blockIdx.x, tid = threadIdx.x;
    const int l = tid & 63, w = tid >> 6;
    const int base = tid * 4;
    int m[4], cnt = 0;
#pragma unroll
    for (int i = 0; i < 4; ++i) {
        int tok = tokens[b * S + base + i];
        m[i] = (tok == EOS) ? 1 : 0;
        cnt += m[i];
    }
    int inc = cnt;
#pragma unroll
    for (int d = 1; d < 64; d <<= 1) {
        int v = __shfl_up(inc, d, 64);
        if (l >= d) inc += v;
    }
    __shared__ int wt[4];
    if (l == 63) wt[w] = inc;
    __syncthreads();
    int off = 0;
    for (int k = 0; k < 4; ++k)
        if (k < w) off += wt[k];
    int run = off + inc - cnt;  // exclusive prefix
#pragma unroll
    for (int i = 0; i < 4; ++i) {
        dest[(base + i) * B + b] = m[i] ? run : -1;
        run += m[i];
    }
}

// ---------------------------------------------------------------------------
// Persistent fused GRU. 128 blocks x 64 threads (one wave each, no LDS).
// Wave wid: unit group j=wid>>2 (units [16j,16j+16)), batch slice w=wid&3
// (batches [16w,16w+16)). Weights register-resident. h exchanged via global
// bf16 hi/lo planes, double-buffered, ALL h/flag traffic as relaxed
// agent-scope atomics (sc1 -> Infinity-Cache coherence point; NO cache-flush
// fences -- round-2's per-step buffer_inv/wbl2 was the 9 us/step cost).
// Slice w only syncs with the 32 waves of slice w.
// ---------------------------------------------------------------------------
__global__ __launch_bounds__(64, 1) void gru_kernel(
    const int* __restrict__ tokens, const float* __restrict__ emb,
    const float* __restrict__ w_ih, const float* __restrict__ w_hh,
    const float* __restrict__ b_ih, const float* __restrict__ b_hh,
    const int* __restrict__ dest,
    unsigned short* hbuf, unsigned int* flags, float* __restrict__ out) {

    const int wid = blockIdx.x;          // 0..127
    const int j = wid >> 2;              // unit group
    const int w = wid & 3;               // batch slice
    const int l = threadIdx.x;           // 0..63
    const int l15 = l & 15, quad = l >> 4;
    const int unit = j * 16 + l15;
    const int koff = quad * 8;
    const int brow = w * 16 + l15;

    // ---- one-time: weight B-fragments into registers (RNE bf16) ----
    bf16x8 Wh[3][16];
#pragma unroll
    for (int g = 0; g < 3; ++g)
#pragma unroll
        for (int kt = 0; kt < 16; ++kt) {
            const float* p = &w_hh[(size_t)(g * H + unit) * H + kt * 32 + koff];
            Wh[g][kt] = pack8rne(*(const float4*)p, *(const float4*)(p + 4));
        }
    bf16x8 Wi[3][8];
#pragma unroll
    for (int g = 0; g < 3; ++g)
#pragma unroll
        for (int kt = 0; kt < 8; ++kt) {
            const float* p = &w_ih[(size_t)(g * H + unit) * E + kt * 32 + koff];
            Wi[g][kt] = pack8rne(*(const float4*)p, *(const float4*)(p + 4));
        }
    const float bi0 = b_ih[unit], bi1 = b_ih[H + unit], bi2 = b_ih[2 * H + unit];
    const float bh0 = b_hh[unit], bh1 = b_hh[H + unit], bh2 = b_hh[2 * H + unit];

    float hown[4] = {0.f, 0.f, 0.f, 0.f};
    int tok_next = tokens[brow * S];
    int budget = 1 << 22;                 // anti-hang safety
    const int myflag = l & 31;            // poll wave (myflag, w)

    for (int t = 0; t < S; ++t) {
        // --- independent work first (hides under producer wait) ---
        const int tok = tok_next;
        const float* er = &emb[(size_t)tok * E + koff];
        float4 ef[8][2];
#pragma unroll
        for (int kt = 0; kt < 8; ++kt) {
            ef[kt][0] = *(const float4*)(er + kt * 32);
            ef[kt][1] = *(const float4*)(er + kt * 32 + 4);
        }
        if (t + 1 < S) tok_next = tokens[brow * S + t + 1];
        int4 dst4 = *(const int4*)&dest[t * B + w * 16 + quad * 4];

        f32x4 gi0 = {bi0, bi0, bi0, bi0};
        f32x4 gi1 = {bi1, bi1, bi1, bi1};
        f32x4 gi2 = {bi2, bi2, bi2, bi2};
#pragma unroll
        for (int kt = 0; kt < 8; ++kt) {
            bf16x8 af = pack8hu(ef[kt][0], ef[kt][1]);
            gi0 = __builtin_amdgcn_mfma_f32_16x16x32_bf16(af, Wi[0][kt], gi0, 0, 0, 0);
            gi1 = __builtin_amdgcn_mfma_f32_16x16x32_bf16(af, Wi[1][kt], gi1, 0, 0, 0);
            gi2 = __builtin_amdgcn_mfma_f32_16x16x32_bf16(af, Wi[2][kt], gi2, 0, 0, 0);
        }

        // --- wait for h[t]: only the 32 producers of batch slice w ---
        while (budget > 0) {
            unsigned int f = AT_LD(&flags[(myflag * 4 + w) * 4]);
            if (__all((int)(f >= (unsigned)t))) break;
            --budget;
        }
        __atomic_signal_fence(__ATOMIC_SEQ_CST);

        // --- gh = b_hh + h . W_hh^T  (bf16 hi+lo split), atomic L3 loads ---
        const unsigned short* hs = hbuf + (size_t)(t & 1) * (2 * B * H);
        f32x4 a0 = {bh0, bh0, bh0, bh0};
        f32x4 a1 = {bh1, bh1, bh1, bh1};
        f32x4 a2 = {bh2, bh2, bh2, bh2};
#pragma unroll
        for (int half = 0; half < 2; ++half) {
            union { unsigned long long q[2]; bf16x8 v; } uh[8], ul[8];
#pragma unroll
            for (int k = 0; k < 8; ++k) {        // batch-issue 32 u64 loads
                const int kt = half * 8 + k;
                const size_t off = (size_t)brow * H + kt * 32 + koff;
                const unsigned long long* ph = (const unsigned long long*)(hs + off);
                const unsigned long long* pl = (const unsigned long long*)(hs + B * H + off);
                uh[k].q[0] = AT_LD(ph);     uh[k].q[1] = AT_LD(ph + 1);
                ul[k].q[0] = AT_LD(pl);     ul[k].q[1] = AT_LD(pl + 1);
            }
#pragma unroll
            for (int k = 0; k < 8; ++k) {
                const int kt = half * 8 + k;
                a0 = __builtin_amdgcn_mfma_f32_16x16x32_bf16(uh[k].v, Wh[0][kt], a0, 0, 0, 0);
                a1 = __builtin_amdgcn_mfma_f32_16x16x32_bf16(uh[k].v, Wh[1][kt], a1, 0, 0, 0);
                a2 = __builtin_amdgcn_mfma_f32_16x16x32_bf16(uh[k].v, Wh[2][kt], a2, 0, 0, 0);
                a0 = __builtin_amdgcn_mfma_f32_16x16x32_bf16(ul[k].v, Wh[0][kt], a0, 0, 0, 0);
                a1 = __builtin_amdgcn_mfma_f32_16x16x32_bf16(ul[k].v, Wh[1][kt], a1, 0, 0, 0);
                a2 = __builtin_amdgcn_mfma_f32_16x16x32_bf16(ul[k].v, Wh[2][kt], a2, 0, 0, 0);
            }
        }

        // --- gates + packed atomic h[t+1] stores (hi|lo paired via shfl) ---
        unsigned short* hd = hbuf + (size_t)((t + 1) & 1) * (2 * B * H);
        unsigned int* hd_hi32 = (unsigned int*)hd;
        unsigned int* hd_lo32 = (unsigned int*)(hd + B * H);
        const bool even = (l15 & 1) == 0;
        int dsts[4] = {dst4.x, dst4.y, dst4.z, dst4.w};
#pragma unroll
        for (int r = 0; r < 4; ++r) {
            const int b = w * 16 + quad * 4 + r;
            float rg = 1.f / (1.f + __expf(-(gi0[r] + a0[r])));
            float zg = 1.f / (1.f + __expf(-(gi1[r] + a1[r])));
            float x = gi2[r] + rg * a2[r];
            x = fminf(15.f, fmaxf(-15.f, x));
            float e = __expf(-2.f * x);
            float ng = (1.f - e) / (1.f + e);
            float h = (1.f - zg) * ng + zg * hown[r];   // fp32 carry (exact)
            hown[r] = h;
            unsigned short hi16 = f2bf(h);
            unsigned short lo16 = f2bf(h - bf2f(hi16));
            unsigned int pk = ((unsigned int)lo16 << 16) | (unsigned int)hi16;
            unsigned int sw = (unsigned int)__shfl_xor((int)pk, 1);
            // even lane -> hi-plane dword (own hi | partner hi)
            // odd  lane -> lo-plane dword (partner lo | own lo)
            unsigned int val = even ? ((pk & 0xFFFFu) | (sw << 16))
                                    : ((sw >> 16) | (pk & 0xFFFF0000u));
            unsigned int didx = ((unsigned int)(b * H + unit)) >> 1;
            unsigned int* plane = even ? hd_hi32 : hd_lo32;
            AT_ST(plane + didx, val);
            if (dsts[r] >= 0)
                out[((size_t)(dsts[r] * B + b)) * H + unit] = h;
        }

        // --- publish: drain stores to coherence point, then flag ---
        __atomic_signal_fence(__ATOMIC_SEQ_CST);
        __builtin_amdgcn_s_waitcnt(0);   // vmcnt(0) lgkmcnt(0) expcnt(0)
        __atomic_signal_fence(__ATOMIC_SEQ_CST);
        if (l == 0)
            AT_ST(&flags[wid * 4], (unsigned int)(t + 1));
    }
}

// ---------------------------------------------------------------------------
// Workspace layout (~784 KB):
//   [0, 2048)               flags: 128 x uint, stride 16B (zeroed)
//   [4096, 4096+512K)       hbuf: 2 bufs x {hi,lo} x [64][512] bf16 (zeroed)
//   [528384, +256K)         dest map [1024][64] int32
// ---------------------------------------------------------------------------
extern "C" void kernel_launch(void* const* d_in, const int* in_sizes, int n_in,
                              void* d_out, int out_size, void* d_ws, size_t ws_size,
                              hipStream_t stream) {
    const int*   tokens = (const int*)d_in[0];
    const float* emb    = (const float*)d_in[1];
    const float* w_ih   = (const float*)d_in[2];
    const float* w_hh   = (const float*)d_in[3];
    const float* b_ih   = (const float*)d_in[4];
    const float* b_hh   = (const float*)d_in[5];
    float* out = (float*)d_out;

    char* ws = (char*)d_ws;
    unsigned int*   flags = (unsigned int*)ws;
    unsigned short* hbuf  = (unsigned short*)(ws + 4096);
    int*            dest  = (int*)(ws + 4096 + 2 * 2 * B * H * sizeof(unsigned short));

    hipMemsetAsync(d_ws, 0, 4096 + 2 * 2 * B * H * sizeof(unsigned short), stream);
    dest_kernel<<<B, 256, 0, stream>>>(tokens, dest);
    gru_kernel<<<NW, 64, 0, stream>>>(tokens, emb, w_ih, w_hh, b_ih, b_hh,
                                      dest, hbuf, flags, out);
}